// Round 1
// baseline (322.632 us; speedup 1.0000x reference)
//
#include <hip/hip_runtime.h>
#include <math.h>

// Problem constants: B=1, L=512, D=1024, NH=16, NKV=4, NR=16, HD=RD=64
#define L 512
#define D 1024
#define NH 16
#define NKV 4
#define NR 16
#define HD 64
#define ATTN_SCALE 0.125f
#define REL_SCALE 0.125f

// ---------------------------------------------------------------------------
// Generic 64x64-tile fp32 GEMM body: C[M,N] += A[M,K] * B[K,N] (row-major,
// arbitrary leading dims). 256 threads, 4x4 micro-tile per thread, K-tiles=16.
// ---------------------------------------------------------------------------
__device__ __forceinline__ void gemm64_body(const float* __restrict__ A,
                                            const float* __restrict__ B,
                                            float* __restrict__ C,
                                            int lda, int ldb, int ldc,
                                            int K, int bm, int bn) {
  __shared__ float As[16][64];  // As[k][m]
  __shared__ float Bs[16][64];  // Bs[k][n]
  const int tid = threadIdx.x;
  const int tx = tid & 15, ty = tid >> 4;
  const int ar = tid >> 2, ac = (tid & 3) << 2;        // A tile: row ar, col ac..ac+3
  const int brow = tid >> 4, bcol = (tid & 15) << 2;   // B tile: row brow, col bcol..+3
  float acc[4][4] = {};
  for (int k0 = 0; k0 < K; k0 += 16) {
    float4 av = *(const float4*)(A + (size_t)(bm + ar) * lda + k0 + ac);
    float4 bv = *(const float4*)(B + (size_t)(k0 + brow) * ldb + bn + bcol);
    __syncthreads();
    As[ac + 0][ar] = av.x; As[ac + 1][ar] = av.y;
    As[ac + 2][ar] = av.z; As[ac + 3][ar] = av.w;
    *(float4*)&Bs[brow][bcol] = bv;
    __syncthreads();
#pragma unroll
    for (int kk = 0; kk < 16; ++kk) {
      float4 a = *(const float4*)&As[kk][ty << 2];
      float4 b = *(const float4*)&Bs[kk][tx << 2];
      acc[0][0] = fmaf(a.x, b.x, acc[0][0]);
      acc[0][1] = fmaf(a.x, b.y, acc[0][1]);
      acc[0][2] = fmaf(a.x, b.z, acc[0][2]);
      acc[0][3] = fmaf(a.x, b.w, acc[0][3]);
      acc[1][0] = fmaf(a.y, b.x, acc[1][0]);
      acc[1][1] = fmaf(a.y, b.y, acc[1][1]);
      acc[1][2] = fmaf(a.y, b.z, acc[1][2]);
      acc[1][3] = fmaf(a.y, b.w, acc[1][3]);
      acc[2][0] = fmaf(a.z, b.x, acc[2][0]);
      acc[2][1] = fmaf(a.z, b.y, acc[2][1]);
      acc[2][2] = fmaf(a.z, b.z, acc[2][2]);
      acc[2][3] = fmaf(a.z, b.w, acc[2][3]);
      acc[3][0] = fmaf(a.w, b.x, acc[3][0]);
      acc[3][1] = fmaf(a.w, b.y, acc[3][1]);
      acc[3][2] = fmaf(a.w, b.z, acc[3][2]);
      acc[3][3] = fmaf(a.w, b.w, acc[3][3]);
    }
  }
  float* Cp = C + (size_t)(bm + (ty << 2)) * ldc + bn + (tx << 2);
#pragma unroll
  for (int ii = 0; ii < 4; ++ii) {
    float4 v = make_float4(acc[ii][0], acc[ii][1], acc[ii][2], acc[ii][3]);
    *(float4*)(Cp + (size_t)ii * ldc) = v;
  }
}

// ---------------------------------------------------------------------------
// Fused projections: z selects which of the 5 input GEMMs this block works on.
//   z=0: q  = x @ wq_attn  (512x1024)     z=1: k  = x @ wk_attn (512x256)
//   z=2: qr = x @ wq_rel   (512x1024)     z=3: kr = x @ wk_rel  (512x1024)
//   z=4: sv = symbols @ wv (512x256)
// ---------------------------------------------------------------------------
__global__ __launch_bounds__(256) void proj_kernel(
    const float* __restrict__ x, const float* __restrict__ symbols,
    const float* __restrict__ wq, const float* __restrict__ wk,
    const float* __restrict__ wqr, const float* __restrict__ wkr,
    const float* __restrict__ wv,
    float* __restrict__ qf, float* __restrict__ kf, float* __restrict__ qr,
    float* __restrict__ kr, float* __restrict__ sv) {
  const int z = blockIdx.z;
  const float* A = x;
  const float* B;
  float* C;
  int N;
  switch (z) {
    case 0: B = wq;  C = qf; N = 1024; break;
    case 1: B = wk;  C = kf; N = 256;  break;
    case 2: B = wqr; C = qr; N = 1024; break;
    case 3: B = wkr; C = kr; N = 1024; break;
    default: A = symbols; B = wv; C = sv; N = 256; break;
  }
  const int bn = blockIdx.x << 6;
  if (bn >= N) return;
  gemm64_body(A, B, C, D, N, N, D, blockIdx.y << 6, bn);
}

// Final projection: out = att @ wo
__global__ __launch_bounds__(256) void gemm_kernel(const float* __restrict__ A,
                                                   const float* __restrict__ B,
                                                   float* __restrict__ C,
                                                   int lda, int ldb, int ldc, int K) {
  gemm64_body(A, B, C, lda, ldb, ldc, K, blockIdx.y << 6, blockIdx.x << 6);
}

// ---------------------------------------------------------------------------
// RoPE (interleaved pairs) applied in place to q (16 heads) and k (4 kv heads).
// pair p: re=t[2p], im=t[2p+1]; out: (re*c - im*s, re*s + im*c)
// ---------------------------------------------------------------------------
__global__ __launch_bounds__(256) void rope_kernel(float* __restrict__ qf,
                                                   float* __restrict__ kf,
                                                   const float* __restrict__ fcos,
                                                   const float* __restrict__ fsin) {
  int idx = blockIdx.x * 256 + threadIdx.x;  // 512*16*32 q-pairs + 512*4*32 k-pairs
  float* base;
  int i, p;
  if (idx < 262144) {
    i = idx >> 9;
    int hp = idx & 511;
    p = hp & 31;
    base = qf + (size_t)i * 1024 + ((hp >> 5) << 6) + (p << 1);
  } else {
    int id2 = idx - 262144;
    i = id2 >> 7;
    int gp = id2 & 127;
    p = gp & 31;
    base = kf + (size_t)i * 256 + ((gp >> 5) << 6) + (p << 1);
  }
  float c = fcos[(i << 5) + p], s = fsin[(i << 5) + p];
  float re = base[0], im = base[1];
  base[0] = fmaf(re, c, -im * s);
  base[1] = fmaf(re, s, im * c);
}

// ---------------------------------------------------------------------------
// Shared 64x64 tile of A(64x64-dot)B^T: both operands row-major [rows][64].
// LDS stored transposed [d][row] (pad 68 keeps float4 alignment + kills the
// worst bank conflicts). acc[ii][jj] = sum_d A[bi+4ty+ii][d]*B[bj+4tx+jj][d].
// ---------------------------------------------------------------------------
__device__ __forceinline__ void dot64_tile(const float* __restrict__ Abase, int lda,
                                           const float* __restrict__ Bbase, int ldb,
                                           float (&acc)[4][4]) {
  __shared__ float Qs[64][68];
  __shared__ float Ks[64][68];
  const int tid = threadIdx.x;
  const int r0 = tid >> 4;
  const int c = (tid & 15) << 2;
#pragma unroll
  for (int t = 0; t < 4; ++t) {
    int rr = r0 + (t << 4);
    float4 av = *(const float4*)(Abase + (size_t)rr * lda + c);
    Qs[c + 0][rr] = av.x; Qs[c + 1][rr] = av.y;
    Qs[c + 2][rr] = av.z; Qs[c + 3][rr] = av.w;
    float4 bv = *(const float4*)(Bbase + (size_t)rr * ldb + c);
    Ks[c + 0][rr] = bv.x; Ks[c + 1][rr] = bv.y;
    Ks[c + 2][rr] = bv.z; Ks[c + 3][rr] = bv.w;
  }
  __syncthreads();
  const int tx = tid & 15, ty = tid >> 4;
#pragma unroll 8
  for (int d = 0; d < 64; ++d) {
    float4 a = *(const float4*)&Qs[d][ty << 2];
    float4 b = *(const float4*)&Ks[d][tx << 2];
    acc[0][0] = fmaf(a.x, b.x, acc[0][0]);
    acc[0][1] = fmaf(a.x, b.y, acc[0][1]);
    acc[0][2] = fmaf(a.x, b.z, acc[0][2]);
    acc[0][3] = fmaf(a.x, b.w, acc[0][3]);
    acc[1][0] = fmaf(a.y, b.x, acc[1][0]);
    acc[1][1] = fmaf(a.y, b.y, acc[1][1]);
    acc[1][2] = fmaf(a.y, b.z, acc[1][2]);
    acc[1][3] = fmaf(a.y, b.w, acc[1][3]);
    acc[2][0] = fmaf(a.z, b.x, acc[2][0]);
    acc[2][1] = fmaf(a.z, b.y, acc[2][1]);
    acc[2][2] = fmaf(a.z, b.z, acc[2][2]);
    acc[2][3] = fmaf(a.z, b.w, acc[2][3]);
    acc[3][0] = fmaf(a.w, b.x, acc[3][0]);
    acc[3][1] = fmaf(a.w, b.y, acc[3][1]);
    acc[3][2] = fmaf(a.w, b.z, acc[3][2]);
    acc[3][3] = fmaf(a.w, b.w, acc[3][3]);
  }
}

// scores[h,i,j] = ATTN_SCALE * q[i,h,:]·k[j,h/4,:]  (lower-triangular tiles only)
__global__ __launch_bounds__(256) void scores_kernel(const float* __restrict__ q,
                                                     const float* __restrict__ k,
                                                     float* __restrict__ attn) {
  const int h = blockIdx.z;
  const int bi = blockIdx.y << 6, bj = blockIdx.x << 6;
  if (bj > bi) return;  // fully-masked tile: softmax writes the zeros
  float acc[4][4] = {};
  dot64_tile(q + (size_t)bi * 1024 + (h << 6), 1024,
             k + (size_t)bj * 256 + ((h >> 2) << 6), 256, acc);
  const int tx = threadIdx.x & 15, ty = threadIdx.x >> 4;
  float* outp = attn + (size_t)h * 262144 + (size_t)(bi + (ty << 2)) * 512 + bj + (tx << 2);
#pragma unroll
  for (int ii = 0; ii < 4; ++ii) {
    float4 v = make_float4(acc[ii][0] * ATTN_SCALE, acc[ii][1] * ATTN_SCALE,
                           acc[ii][2] * ATTN_SCALE, acc[ii][3] * ATTN_SCALE);
    *(float4*)(outp + (size_t)ii * 512) = v;
  }
}

// relations[i,j,r] = REL_SCALE * qr[i,r,:]·kr[j,r,:]  (full, unmasked)
__global__ __launch_bounds__(256) void relations_kernel(const float* __restrict__ qr,
                                                        const float* __restrict__ kr,
                                                        float* __restrict__ rel) {
  const int r = blockIdx.z;
  const int bi = blockIdx.y << 6, bj = blockIdx.x << 6;
  float acc[4][4] = {};
  dot64_tile(qr + (size_t)bi * 1024 + (r << 6), 1024,
             kr + (size_t)bj * 1024 + (r << 6), 1024, acc);
  const int tx = threadIdx.x & 15, ty = threadIdx.x >> 4;
#pragma unroll
  for (int ii = 0; ii < 4; ++ii) {
    size_t rowo = (size_t)(bi + (ty << 2) + ii) * 8192 + r;
#pragma unroll
    for (int jj = 0; jj < 4; ++jj)
      rel[rowo + (size_t)(bj + (tx << 2) + jj) * 16] = acc[ii][jj] * REL_SCALE;
  }
}

// Row softmax with causal mask; writes exact zeros for j > i (attn is an output).
__global__ __launch_bounds__(256) void softmax_kernel(float* __restrict__ attn) {
  const int i = blockIdx.x, h = blockIdx.y;
  float* row = attn + (size_t)h * 262144 + (size_t)i * 512;
  const int tid = threadIdx.x;
  const int n = i + 1;
  float v0 = (tid < n) ? row[tid] : -INFINITY;
  float v1 = (tid + 256 < n) ? row[tid + 256] : -INFINITY;
  float m = fmaxf(v0, v1);
#pragma unroll
  for (int off = 32; off; off >>= 1) m = fmaxf(m, __shfl_down(m, off));
  __shared__ float redm[4];
  __shared__ float reds[4];
  if ((tid & 63) == 0) redm[tid >> 6] = m;
  __syncthreads();
  m = fmaxf(fmaxf(redm[0], redm[1]), fmaxf(redm[2], redm[3]));
  float e0 = (tid < n) ? __expf(v0 - m) : 0.f;
  float e1 = (tid + 256 < n) ? __expf(v1 - m) : 0.f;
  float s = e0 + e1;
#pragma unroll
  for (int off = 32; off; off >>= 1) s += __shfl_down(s, off);
  if ((tid & 63) == 0) reds[tid >> 6] = s;
  __syncthreads();
  s = reds[0] + reds[1] + reds[2] + reds[3];
  float inv = 1.f / s;
  row[tid] = e0 * inv;
  row[tid + 256] = e1 * inv;
}

// attended_symbols[i,h,:] = sum_j attn[h,i,j] * sv[j,h/4,:]; K capped causally.
__global__ __launch_bounds__(256) void asym_kernel(const float* __restrict__ attn,
                                                   const float* __restrict__ sv,
                                                   float* __restrict__ asym) {
  const int bi = blockIdx.x << 6;
  const int h = blockIdx.y;
  gemm64_body(attn + (size_t)h * 262144, sv + ((h >> 2) << 6), asym + (h << 6),
              512, 256, 1024, bi + 64 /*causal K cap*/, bi, 0);
}

// T[i,h,r] = sum_j attn[h,i,j] * rel[i,j,r]   (512 x 16 x 16)
__global__ __launch_bounds__(256) void tker(const float* __restrict__ attn,
                                            const float* __restrict__ rel,
                                            float* __restrict__ T) {
  const int i = blockIdx.x;
  const int tid = threadIdx.x;
  __shared__ float a_s[16][128];
  __shared__ float r_s[128][16];
  const int h = tid >> 4, r = tid & 15;
  float acc = 0.f;
  for (int j0 = 0; j0 <= i; j0 += 128) {
#pragma unroll
    for (int idx = tid; idx < 512; idx += 256) {
      int hh = idx >> 5;
      int j4 = (idx & 31) << 2;
      *(float4*)&a_s[hh][j4] =
          *(const float4*)(attn + (size_t)hh * 262144 + (size_t)i * 512 + j0 + j4);
    }
#pragma unroll
    for (int idx = tid; idx < 512; idx += 256)
      *(float4*)(&r_s[0][0] + (idx << 2)) =
          *(const float4*)(rel + (size_t)i * 8192 + ((size_t)j0 << 4) + (idx << 2));
    __syncthreads();
#pragma unroll 8
    for (int jj = 0; jj < 128; ++jj)  // attn beyond i is exactly 0 -> safe
      acc = fmaf(a_s[h][jj], r_s[jj][r], acc);
    __syncthreads();
  }
  T[(size_t)i * 256 + tid] = acc;
}

// att[i,h,d] = asym[i,h,d] + sum_r T[i,h,r]*wr[r,h*64+d]
__global__ __launch_bounds__(256) void combine_kernel(const float* __restrict__ asym,
                                                      const float* __restrict__ T,
                                                      const float* __restrict__ wr,
                                                      float* __restrict__ att) {
  const int i = blockIdx.x;
  const int tid = threadIdx.x;
  const int h = tid >> 4, d0 = (tid & 15) << 2;
  const float* t = T + (size_t)i * 256 + h * 16;
  float4 acc = *(const float4*)(asym + (size_t)i * 1024 + (h << 6) + d0);
#pragma unroll
  for (int r = 0; r < 16; ++r) {
    float tv = t[r];
    float4 w = *(const float4*)(wr + (size_t)r * 1024 + (h << 6) + d0);
    acc.x = fmaf(tv, w.x, acc.x);
    acc.y = fmaf(tv, w.y, acc.y);
    acc.z = fmaf(tv, w.z, acc.z);
    acc.w = fmaf(tv, w.w, acc.w);
  }
  *(float4*)(att + (size_t)i * 1024 + (h << 6) + d0) = acc;
}

extern "C" void kernel_launch(void* const* d_in, const int* in_sizes, int n_in,
                              void* d_out, int out_size, void* d_ws, size_t ws_size,
                              hipStream_t stream) {
  const float* x       = (const float*)d_in[0];
  const float* symbols = (const float*)d_in[1];
  const float* fcos    = (const float*)d_in[2];
  const float* fsin    = (const float*)d_in[3];
  const float* wq_attn = (const float*)d_in[4];
  const float* wk_attn = (const float*)d_in[5];
  const float* wq_rel  = (const float*)d_in[6];
  const float* wk_rel  = (const float*)d_in[7];
  const float* wr      = (const float*)d_in[8];
  const float* wv      = (const float*)d_in[9];
  const float* wo      = (const float*)d_in[10];

  float* out  = (float*)d_out;            // 512*1024
  float* attn = out + 524288;             // 16*512*512
  float* rel  = attn + 4194304;           // 512*512*16

  // workspace (7.34 MB of fp32), with safe aliasing:
  float* ws  = (float*)d_ws;
  float* qf  = ws;                // 524288  (dead after scores_kernel)
  float* kf  = qf + 524288;       // 131072  (dead after scores_kernel)
  float* qr  = kf + 131072;       // 524288  (dead after relations_kernel)
  float* kr  = qr + 524288;       // 524288
  float* sv  = kr + 524288;       // 131072
  float* asym = qr;               // alias: written after qr last read
  float* T    = kf;               // alias: written after kf last read
  float* att  = qf;               // alias: written after qf last read

  proj_kernel<<<dim3(16, 8, 5), 256, 0, stream>>>(x, symbols, wq_attn, wk_attn,
                                                  wq_rel, wk_rel, wv,
                                                  qf, kf, qr, kr, sv);
  rope_kernel<<<dim3(1280), 256, 0, stream>>>(qf, kf, fcos, fsin);
  scores_kernel<<<dim3(8, 8, 16), 256, 0, stream>>>(qf, kf, attn);
  softmax_kernel<<<dim3(512, 16), 256, 0, stream>>>(attn);
  relations_kernel<<<dim3(8, 8, 16), 256, 0, stream>>>(qr, kr, rel);
  asym_kernel<<<dim3(8, 16), 256, 0, stream>>>(attn, sv, asym);
  tker<<<dim3(512), 256, 0, stream>>>(attn, rel, T);
  combine_kernel<<<dim3(512), 256, 0, stream>>>(asym, T, wr, att);
  gemm_kernel<<<dim3(16, 8), 256, 0, stream>>>(att, wo, out, 1024, 1024, 1024, 1024);
}

// Round 2
// 196.562 us; speedup vs baseline: 1.6414x; 1.6414x over previous
//
#include <hip/hip_runtime.h>
#include <math.h>

// B=1, L=512, D=1024, NH=16, NKV=4, NR=16, HD=RD=64
#define ATTN_SCALE 0.125f
#define REL_SCALE 0.125f

using ushort = unsigned short;
using bf16x8 = __attribute__((ext_vector_type(8))) __bf16;
using floatx4 = __attribute__((ext_vector_type(4))) float;
using ushort8 = __attribute__((ext_vector_type(8))) ushort;

__device__ __forceinline__ ushort f2bf(float x) {
  unsigned int u = __builtin_bit_cast(unsigned int, x);
  u += 0x7fffu + ((u >> 16) & 1u);  // RNE
  return (ushort)(u >> 16);
}
__device__ __forceinline__ float bf2f(ushort h) {
  return __builtin_bit_cast(float, (unsigned int)h << 16);
}

// ---------------------------------------------------------------------------
// Shared MFMA GEMM body: C64x64 = A[64 rows][K] * Bt[64 cols][K]^T, bf16 MFMA.
// A: row-major [rows][K] (bf16, or fp32 converted during staging if AF32).
// Bt: row-major [cols][K] bf16 (i.e. B transposed).
// Block = 256 thr = 4 waves in 2x2; wave tile 32x32 = 2x2 MFMA subtiles.
// LDS rows padded to 72 bf16 (144 B): frag-read lanes land 2-way/bank (free).
// ---------------------------------------------------------------------------
template <bool AF32>
__device__ __forceinline__ void mfma_body(const void* __restrict__ Av, int lda,
                                          const ushort* __restrict__ Bt, int ldb,
                                          int K, floatx4 (&acc)[2][2]) {
  __shared__ ushort As[64][72];
  __shared__ ushort Bs[64][72];
  const int tid = threadIdx.x;
  const int sr = tid >> 2, sc = (tid & 3) << 4;  // staging: row, 16-elem chunk
  const int lane = tid & 63;
  const int wy = (tid >> 7) & 1, wx = (tid >> 6) & 1;
  const int lm = lane & 15, lq = lane >> 4;
  const ushort* a_rd = &As[32 * wy + lm][lq * 8];
  const ushort* b_rd = &Bs[32 * wx + lm][lq * 8];
  for (int k0 = 0; k0 < K; k0 += 64) {
    ushort8 av0, av1;
    if constexpr (AF32) {
      const float* Ap = (const float*)Av + (size_t)sr * lda + k0 + sc;
      float4 f0 = *(const float4*)(Ap);
      float4 f1 = *(const float4*)(Ap + 4);
      float4 f2 = *(const float4*)(Ap + 8);
      float4 f3 = *(const float4*)(Ap + 12);
      av0 = ushort8{f2bf(f0.x), f2bf(f0.y), f2bf(f0.z), f2bf(f0.w),
                    f2bf(f1.x), f2bf(f1.y), f2bf(f1.z), f2bf(f1.w)};
      av1 = ushort8{f2bf(f2.x), f2bf(f2.y), f2bf(f2.z), f2bf(f2.w),
                    f2bf(f3.x), f2bf(f3.y), f2bf(f3.z), f2bf(f3.w)};
    } else {
      const ushort* Ap = (const ushort*)Av + (size_t)sr * lda + k0 + sc;
      av0 = *(const ushort8*)Ap;
      av1 = *(const ushort8*)(Ap + 8);
    }
    const ushort* Bp = Bt + (size_t)sr * ldb + k0 + sc;
    ushort8 bv0 = *(const ushort8*)Bp;
    ushort8 bv1 = *(const ushort8*)(Bp + 8);
    __syncthreads();
    *(ushort8*)&As[sr][sc] = av0;
    *(ushort8*)&As[sr][sc + 8] = av1;
    *(ushort8*)&Bs[sr][sc] = bv0;
    *(ushort8*)&Bs[sr][sc + 8] = bv1;
    __syncthreads();
#pragma unroll
    for (int kh = 0; kh < 2; ++kh) {
      bf16x8 a0 = *(const bf16x8*)(a_rd + kh * 32);
      bf16x8 a1 = *(const bf16x8*)(a_rd + 16 * 72 + kh * 32);
      bf16x8 b0 = *(const bf16x8*)(b_rd + kh * 32);
      bf16x8 b1 = *(const bf16x8*)(b_rd + 16 * 72 + kh * 32);
      acc[0][0] = __builtin_amdgcn_mfma_f32_16x16x32_bf16(a0, b0, acc[0][0], 0, 0, 0);
      acc[0][1] = __builtin_amdgcn_mfma_f32_16x16x32_bf16(a0, b1, acc[0][1], 0, 0, 0);
      acc[1][0] = __builtin_amdgcn_mfma_f32_16x16x32_bf16(a1, b0, acc[1][0], 0, 0, 0);
      acc[1][1] = __builtin_amdgcn_mfma_f32_16x16x32_bf16(a1, b1, acc[1][1], 0, 0, 0);
    }
  }
}

// C/D layout (verified m89): col = lane&15, row = (lane>>4)*4 + reg.
#define EPILOG_VARS                                              \
  const int lane = threadIdx.x & 63;                             \
  const int wy = (threadIdx.x >> 7) & 1, wx = (threadIdx.x >> 6) & 1; \
  const int lm = lane & 15, lq = lane >> 4;

// ---------------------------------------------------------------------------
// Prep: fp32 -> bf16 conversions
// ---------------------------------------------------------------------------
__global__ __launch_bounds__(256) void convert_kernel(const float* __restrict__ x,
                                                      const float* __restrict__ sym,
                                                      ushort* __restrict__ xb,
                                                      ushort* __restrict__ symb) {
  int idx = blockIdx.x * 256 + threadIdx.x;
  int i4 = idx << 2;
  float4 v = *(const float4*)(x + i4);
  uint2 o;
  o.x = (unsigned)f2bf(v.x) | ((unsigned)f2bf(v.y) << 16);
  o.y = (unsigned)f2bf(v.z) | ((unsigned)f2bf(v.w) << 16);
  *(uint2*)(xb + i4) = o;
  float4 w = *(const float4*)(sym + i4);
  o.x = (unsigned)f2bf(w.x) | ((unsigned)f2bf(w.y) << 16);
  o.y = (unsigned)f2bf(w.z) | ((unsigned)f2bf(w.w) << 16);
  *(uint2*)(symb + i4) = o;
}

// Weight transpose+convert: out[n][k] = bf16(in[k][n]), K = 1024 for all.
__global__ __launch_bounds__(256) void wtrans_kernel(
    const float* __restrict__ wq, const float* __restrict__ wk,
    const float* __restrict__ wqr, const float* __restrict__ wkr,
    const float* __restrict__ wv, const float* __restrict__ wo,
    ushort* __restrict__ wqT, ushort* __restrict__ wkT, ushort* __restrict__ wqrT,
    ushort* __restrict__ wkrT, ushort* __restrict__ wvT, ushort* __restrict__ woT) {
  __shared__ ushort t[32][33];
  const float* in;
  ushort* out;
  int N;
  switch (blockIdx.z) {
    case 0: in = wq;  out = wqT;  N = 1024; break;
    case 1: in = wk;  out = wkT;  N = 256;  break;
    case 2: in = wqr; out = wqrT; N = 1024; break;
    case 3: in = wkr; out = wkrT; N = 1024; break;
    case 4: in = wv;  out = wvT;  N = 256;  break;
    default: in = wo; out = woT;  N = 1024; break;
  }
  int n0 = blockIdx.x << 5;
  if (n0 >= N) return;
  int k0 = blockIdx.y << 5;
  int tx = threadIdx.x & 31, ty = threadIdx.x >> 5;
#pragma unroll
  for (int rr = 0; rr < 32; rr += 8)
    t[ty + rr][tx] = f2bf(in[(size_t)(k0 + ty + rr) * N + n0 + tx]);
  __syncthreads();
#pragma unroll
  for (int rr = 0; rr < 32; rr += 8)
    out[(size_t)(n0 + ty + rr) * 1024 + k0 + tx] = t[tx][ty + rr];
}

// svb [512][256] bf16 -> svT [256][512] bf16
__global__ __launch_bounds__(256) void strans_kernel(const ushort* __restrict__ svb,
                                                     ushort* __restrict__ svT) {
  __shared__ ushort t[32][33];
  int n0 = blockIdx.x << 5;  // over 256
  int k0 = blockIdx.y << 5;  // over 512
  int tx = threadIdx.x & 31, ty = threadIdx.x >> 5;
#pragma unroll
  for (int rr = 0; rr < 32; rr += 8)
    t[ty + rr][tx] = svb[(size_t)(k0 + ty + rr) * 256 + n0 + tx];
  __syncthreads();
#pragma unroll
  for (int rr = 0; rr < 32; rr += 8)
    svT[(size_t)(n0 + ty + rr) * 512 + k0 + tx] = t[tx][ty + rr];
}

// ---------------------------------------------------------------------------
// Fused projections (bf16 MFMA): z = {q, k, qr, kr, sv}
// ---------------------------------------------------------------------------
__global__ __launch_bounds__(256) void proj_mfma(
    const ushort* __restrict__ xb, const ushort* __restrict__ symb,
    const ushort* __restrict__ wqT, const ushort* __restrict__ wkT,
    const ushort* __restrict__ wqrT, const ushort* __restrict__ wkrT,
    const ushort* __restrict__ wvT,
    ushort* __restrict__ qb, ushort* __restrict__ kb, ushort* __restrict__ qrb,
    ushort* __restrict__ krb, ushort* __restrict__ svb) {
  const ushort* A = xb;
  const ushort* Bt;
  ushort* C;
  int N;
  switch (blockIdx.z) {
    case 0: Bt = wqT;  C = qb;  N = 1024; break;
    case 1: Bt = wkT;  C = kb;  N = 256;  break;
    case 2: Bt = wqrT; C = qrb; N = 1024; break;
    case 3: Bt = wkrT; C = krb; N = 1024; break;
    default: A = symb; Bt = wvT; C = svb; N = 256; break;
  }
  const int bn = blockIdx.x << 6;
  if (bn >= N) return;
  const int bm = blockIdx.y << 6;
  floatx4 acc[2][2] = {};
  mfma_body<false>(A + (size_t)bm * 1024, 1024, Bt + (size_t)bn * 1024, 1024, 1024, acc);
  EPILOG_VARS
#pragma unroll
  for (int sy = 0; sy < 2; ++sy)
#pragma unroll
    for (int sx = 0; sx < 2; ++sx)
#pragma unroll
      for (int e = 0; e < 4; ++e) {
        int row = bm + 32 * wy + 16 * sy + 4 * lq + e;
        int col = bn + 32 * wx + 16 * sx + lm;
        C[(size_t)row * N + col] = f2bf(acc[sy][sx][e]);
      }
}

// RoPE in place on bf16 q (16 heads) / k (4 kv heads)
__global__ __launch_bounds__(256) void rope_kernel(ushort* __restrict__ qb,
                                                   ushort* __restrict__ kb,
                                                   const float* __restrict__ fcos,
                                                   const float* __restrict__ fsin) {
  int idx = blockIdx.x * 256 + threadIdx.x;
  unsigned int* base;
  int i, p;
  if (idx < 262144) {
    i = idx >> 9;
    int hp = idx & 511;
    p = hp & 31;
    base = (unsigned int*)qb + (i << 9) + ((hp >> 5) << 5) + p;
  } else {
    int id2 = idx - 262144;
    i = id2 >> 7;
    int gp = id2 & 127;
    p = gp & 31;
    base = (unsigned int*)kb + (i << 7) + ((gp >> 5) << 5) + p;
  }
  float c = fcos[(i << 5) + p], s = fsin[(i << 5) + p];
  unsigned int u = *base;
  float re = bf2f((ushort)(u & 0xffff)), im = bf2f((ushort)(u >> 16));
  float o0 = fmaf(re, c, -im * s);
  float o1 = fmaf(re, s, im * c);
  *base = (unsigned int)f2bf(o0) | ((unsigned int)f2bf(o1) << 16);
}

// scores (pre-softmax) into attn buffer; lower-triangular tiles only
__global__ __launch_bounds__(256) void scores_mfma(const ushort* __restrict__ qb,
                                                   const ushort* __restrict__ kb,
                                                   float* __restrict__ attn) {
  const int h = blockIdx.z;
  const int bi = blockIdx.y << 6, bj = blockIdx.x << 6;
  if (bj > bi) return;
  floatx4 acc[2][2] = {};
  mfma_body<false>(qb + (size_t)bi * 1024 + (h << 6), 1024,
                   kb + (size_t)bj * 256 + ((h >> 2) << 6), 256, 64, acc);
  EPILOG_VARS
  float* base = attn + (size_t)h * 262144;
#pragma unroll
  for (int sy = 0; sy < 2; ++sy)
#pragma unroll
    for (int sx = 0; sx < 2; ++sx)
#pragma unroll
      for (int e = 0; e < 4; ++e) {
        int row = bi + 32 * wy + 16 * sy + 4 * lq + e;
        int col = bj + 32 * wx + 16 * sx + lm;
        base[(size_t)row * 512 + col] = acc[sy][sx][e] * ATTN_SCALE;
      }
}

// relations[i,j,r] (fp32 output, r-major innermost)
__global__ __launch_bounds__(256) void relations_mfma(const ushort* __restrict__ qrb,
                                                      const ushort* __restrict__ krb,
                                                      float* __restrict__ rel) {
  const int r = blockIdx.z;
  const int bi = blockIdx.y << 6, bj = blockIdx.x << 6;
  floatx4 acc[2][2] = {};
  mfma_body<false>(qrb + (size_t)bi * 1024 + (r << 6), 1024,
                   krb + (size_t)bj * 1024 + (r << 6), 1024, 64, acc);
  EPILOG_VARS
#pragma unroll
  for (int sy = 0; sy < 2; ++sy)
#pragma unroll
    for (int sx = 0; sx < 2; ++sx)
#pragma unroll
      for (int e = 0; e < 4; ++e) {
        int row = bi + 32 * wy + 16 * sy + 4 * lq + e;
        int col = bj + 32 * wx + 16 * sx + lm;
        rel[((size_t)row * 512 + col) * 16 + r] = acc[sy][sx][e] * REL_SCALE;
      }
}

// Row softmax with causal mask; exact zeros above diagonal (attn is an output).
__global__ __launch_bounds__(256) void softmax_kernel(float* __restrict__ attn) {
  const int i = blockIdx.x, h = blockIdx.y;
  float* row = attn + (size_t)h * 262144 + (size_t)i * 512;
  const int tid = threadIdx.x;
  const int n = i + 1;
  float v0 = (tid < n) ? row[tid] : -INFINITY;
  float v1 = (tid + 256 < n) ? row[tid + 256] : -INFINITY;
  float m = fmaxf(v0, v1);
#pragma unroll
  for (int off = 32; off; off >>= 1) m = fmaxf(m, __shfl_down(m, off));
  __shared__ float redm[4];
  __shared__ float reds[4];
  if ((tid & 63) == 0) redm[tid >> 6] = m;
  __syncthreads();
  m = fmaxf(fmaxf(redm[0], redm[1]), fmaxf(redm[2], redm[3]));
  float e0 = (tid < n) ? __expf(v0 - m) : 0.f;
  float e1 = (tid + 256 < n) ? __expf(v1 - m) : 0.f;
  float s = e0 + e1;
#pragma unroll
  for (int off = 32; off; off >>= 1) s += __shfl_down(s, off);
  if ((tid & 63) == 0) reds[tid >> 6] = s;
  __syncthreads();
  s = reds[0] + reds[1] + reds[2] + reds[3];
  float inv = 1.f / s;
  row[tid] = e0 * inv;
  row[tid + 256] = e1 * inv;
}

// attended_symbols = attn[h] @ sv[:, kv(h)]: fp32 A (converted in staging), causal K cap
__global__ __launch_bounds__(256) void asym_mfma(const float* __restrict__ attn,
                                                 const ushort* __restrict__ svT,
                                                 float* __restrict__ asym) {
  const int bi = blockIdx.x << 6;
  const int h = blockIdx.y;
  floatx4 acc[2][2] = {};
  mfma_body<true>(attn + (size_t)h * 262144 + (size_t)bi * 512, 512,
                  svT + (size_t)(h >> 2) * 32768, 512, bi + 64, acc);
  EPILOG_VARS
#pragma unroll
  for (int sy = 0; sy < 2; ++sy)
#pragma unroll
    for (int sx = 0; sx < 2; ++sx)
#pragma unroll
      for (int e = 0; e < 4; ++e) {
        int row = bi + 32 * wy + 16 * sy + 4 * lq + e;
        int col = 32 * wx + 16 * sx + lm;
        asym[(size_t)row * 1024 + (h << 6) + col] = acc[sy][sx][e];
      }
}

// T[i,h,r] = sum_j attn[h,i,j] * rel[i,j,r]
__global__ __launch_bounds__(256) void tker(const float* __restrict__ attn,
                                            const float* __restrict__ rel,
                                            float* __restrict__ T) {
  const int i = blockIdx.x;
  const int tid = threadIdx.x;
  __shared__ float a_s[16][128];
  __shared__ float r_s[128][16];
  const int h = tid >> 4, r = tid & 15;
  float acc = 0.f;
  for (int j0 = 0; j0 <= i; j0 += 128) {
#pragma unroll
    for (int idx = tid; idx < 512; idx += 256) {
      int hh = idx >> 5;
      int j4 = (idx & 31) << 2;
      *(float4*)&a_s[hh][j4] =
          *(const float4*)(attn + (size_t)hh * 262144 + (size_t)i * 512 + j0 + j4);
    }
#pragma unroll
    for (int idx = tid; idx < 512; idx += 256)
      *(float4*)(&r_s[0][0] + (idx << 2)) =
          *(const float4*)(rel + (size_t)i * 8192 + ((size_t)j0 << 4) + (idx << 2));
    __syncthreads();
#pragma unroll 8
    for (int jj = 0; jj < 128; ++jj)  // attn beyond i is exactly 0 -> safe
      acc = fmaf(a_s[h][jj], r_s[jj][r], acc);
    __syncthreads();
  }
  T[(size_t)i * 256 + tid] = acc;
}

// att[i,h,d] = asym[i,h,d] + sum_r T[i,h,r]*wr[r,h*64+d]  (fp32 out)
__global__ __launch_bounds__(256) void combine_kernel(const float* __restrict__ asym,
                                                      const float* __restrict__ T,
                                                      const float* __restrict__ wr,
                                                      float* __restrict__ att) {
  const int i = blockIdx.x;
  const int tid = threadIdx.x;
  const int h = tid >> 4, d0 = (tid & 15) << 2;
  const float* t = T + (size_t)i * 256 + h * 16;
  float4 acc = *(const float4*)(asym + (size_t)i * 1024 + (h << 6) + d0);
#pragma unroll
  for (int r = 0; r < 16; ++r) {
    float tv = t[r];
    float4 w = *(const float4*)(wr + (size_t)r * 1024 + (h << 6) + d0);
    acc.x = fmaf(tv, w.x, acc.x);
    acc.y = fmaf(tv, w.y, acc.y);
    acc.z = fmaf(tv, w.z, acc.z);
    acc.w = fmaf(tv, w.w, acc.w);
  }
  *(float4*)(att + (size_t)i * 1024 + (h << 6) + d0) = acc;
}

// out = att @ wo (fp32 A converted in staging)
__global__ __launch_bounds__(256) void out_mfma(const float* __restrict__ att,
                                                const ushort* __restrict__ woT,
                                                float* __restrict__ out) {
  const int bn = blockIdx.x << 6, bm = blockIdx.y << 6;
  floatx4 acc[2][2] = {};
  mfma_body<true>(att + (size_t)bm * 1024, 1024, woT + (size_t)bn * 1024, 1024, 1024, acc);
  EPILOG_VARS
#pragma unroll
  for (int sy = 0; sy < 2; ++sy)
#pragma unroll
    for (int sx = 0; sx < 2; ++sx)
#pragma unroll
      for (int e = 0; e < 4; ++e) {
        int row = bm + 32 * wy + 16 * sy + 4 * lq + e;
        int col = bn + 32 * wx + 16 * sx + lm;
        out[(size_t)row * 1024 + col] = acc[sy][sx][e];
      }
}

extern "C" void kernel_launch(void* const* d_in, const int* in_sizes, int n_in,
                              void* d_out, int out_size, void* d_ws, size_t ws_size,
                              hipStream_t stream) {
  const float* x       = (const float*)d_in[0];
  const float* symbols = (const float*)d_in[1];
  const float* fcos    = (const float*)d_in[2];
  const float* fsin    = (const float*)d_in[3];
  const float* wq_attn = (const float*)d_in[4];
  const float* wk_attn = (const float*)d_in[5];
  const float* wq_rel  = (const float*)d_in[6];
  const float* wk_rel  = (const float*)d_in[7];
  const float* wr      = (const float*)d_in[8];
  const float* wv      = (const float*)d_in[9];
  const float* wo      = (const float*)d_in[10];

  float* out  = (float*)d_out;   // 512*1024
  float* attn = out + 524288;    // 16*512*512
  float* rel  = attn + 4194304;  // 512*512*16

  // workspace layout (14.75 MB), with aliasing onto dead regions:
  char* wsb = (char*)d_ws;
  const size_t MB = 1 << 20;
  ushort* xb   = (ushort*)(wsb);                       // 1 MB (dead after proj)
  ushort* symb = (ushort*)(wsb + 1 * MB);              // 1 MB (dead after proj)
  ushort* wqT  = (ushort*)(wsb + 2 * MB);              // 2 MB (dead after proj)
  ushort* wkT  = (ushort*)(wsb + 4 * MB);              // 0.5 MB (dead after proj)
  ushort* wqrT = (ushort*)(wsb + 4 * MB + 512 * 1024); // 2 MB
  ushort* wkrT = (ushort*)(wsb + 6 * MB + 512 * 1024); // 2 MB
  ushort* wvT  = (ushort*)(wsb + 8 * MB + 512 * 1024); // 0.5 MB
  ushort* woT  = (ushort*)(wsb + 9 * MB);              // 2 MB
  ushort* qb   = (ushort*)(wsb + 11 * MB);             // 1 MB
  ushort* kb   = (ushort*)(wsb + 12 * MB);             // 0.25 MB
  ushort* qrb  = (ushort*)(wsb + 12 * MB + 256 * 1024);// 1 MB
  ushort* krb  = (ushort*)(wsb + 13 * MB + 256 * 1024);// 1 MB
  ushort* svb  = (ushort*)(wsb + 14 * MB + 256 * 1024);// 0.25 MB
  ushort* svT  = (ushort*)(wsb + 14 * MB + 512 * 1024);// 0.25 MB
  float*  att  = (float*)(wsb);          // 2 MB, aliases xb+symb (safe: written at combine)
  float*  asym = (float*)(wsb + 2 * MB); // 2 MB, aliases wqT   (safe: written at asym_mfma)
  float*  T    = (float*)(wsb + 4 * MB); // 0.5 MB, aliases wkT (safe: written at tker)

  convert_kernel<<<dim3(512), 256, 0, stream>>>(x, symbols, xb, symb);
  wtrans_kernel<<<dim3(32, 32, 6), 256, 0, stream>>>(wq_attn, wk_attn, wq_rel, wk_rel,
                                                     wv, wo, wqT, wkT, wqrT, wkrT, wvT, woT);
  proj_mfma<<<dim3(16, 8, 5), 256, 0, stream>>>(xb, symb, wqT, wkT, wqrT, wkrT, wvT,
                                                qb, kb, qrb, krb, svb);
  rope_kernel<<<dim3(1280), 256, 0, stream>>>(qb, kb, fcos, fsin);
  strans_kernel<<<dim3(8, 16), 256, 0, stream>>>(svb, svT);
  scores_mfma<<<dim3(8, 8, 16), 256, 0, stream>>>(qb, kb, attn);
  softmax_kernel<<<dim3(512, 16), 256, 0, stream>>>(attn);
  relations_mfma<<<dim3(8, 8, 16), 256, 0, stream>>>(qrb, krb, rel);
  asym_mfma<<<dim3(8, 16), 256, 0, stream>>>(attn, svT, asym);
  tker<<<dim3(512), 256, 0, stream>>>(attn, rel, T);
  combine_kernel<<<dim3(512), 256, 0, stream>>>(asym, T, wr, att);
  out_mfma<<<dim3(16, 8), 256, 0, stream>>>(att, woT, out);
}

// Round 3
// 169.294 us; speedup vs baseline: 1.9058x; 1.1611x over previous
//
#include <hip/hip_runtime.h>
#include <math.h>

// B=1, L=512, D=1024, NH=16, NKV=4, NR=16, HD=RD=64
#define ATTN_SCALE 0.125f
#define REL_SCALE 0.125f

using ushort = unsigned short;
using bf16x8 = __attribute__((ext_vector_type(8))) __bf16;
using floatx4 = __attribute__((ext_vector_type(4))) float;
using ushort8 = __attribute__((ext_vector_type(8))) ushort;
using ushort4v = __attribute__((ext_vector_type(4))) ushort;

__device__ __forceinline__ ushort f2bf(float x) {
  unsigned int u = __builtin_bit_cast(unsigned int, x);
  u += 0x7fffu + ((u >> 16) & 1u);  // RNE
  return (ushort)(u >> 16);
}
__device__ __forceinline__ float bf2f(ushort h) {
  return __builtin_bit_cast(float, (unsigned int)h << 16);
}

// ---------------------------------------------------------------------------
// 64x64 MFMA GEMM body (used by proj and out): C = A[64][K] * Bt[64][K]^T.
// ---------------------------------------------------------------------------
template <bool AF32>
__device__ __forceinline__ void mfma_body(const void* __restrict__ Av, int lda,
                                          const ushort* __restrict__ Bt, int ldb,
                                          int K, floatx4 (&acc)[2][2]) {
  __shared__ ushort As[64][72];
  __shared__ ushort Bs[64][72];
  const int tid = threadIdx.x;
  const int sr = tid >> 2, sc = (tid & 3) << 4;
  const int lane = tid & 63;
  const int wy = (tid >> 7) & 1, wx = (tid >> 6) & 1;
  const int lm = lane & 15, lq = lane >> 4;
  const ushort* a_rd = &As[32 * wy + lm][lq * 8];
  const ushort* b_rd = &Bs[32 * wx + lm][lq * 8];
  for (int k0 = 0; k0 < K; k0 += 64) {
    ushort8 av0, av1;
    if constexpr (AF32) {
      const float* Ap = (const float*)Av + (size_t)sr * lda + k0 + sc;
      float4 f0 = *(const float4*)(Ap);
      float4 f1 = *(const float4*)(Ap + 4);
      float4 f2 = *(const float4*)(Ap + 8);
      float4 f3 = *(const float4*)(Ap + 12);
      av0 = ushort8{f2bf(f0.x), f2bf(f0.y), f2bf(f0.z), f2bf(f0.w),
                    f2bf(f1.x), f2bf(f1.y), f2bf(f1.z), f2bf(f1.w)};
      av1 = ushort8{f2bf(f2.x), f2bf(f2.y), f2bf(f2.z), f2bf(f2.w),
                    f2bf(f3.x), f2bf(f3.y), f2bf(f3.z), f2bf(f3.w)};
    } else {
      const ushort* Ap = (const ushort*)Av + (size_t)sr * lda + k0 + sc;
      av0 = *(const ushort8*)Ap;
      av1 = *(const ushort8*)(Ap + 8);
    }
    const ushort* Bp = Bt + (size_t)sr * ldb + k0 + sc;
    ushort8 bv0 = *(const ushort8*)Bp;
    ushort8 bv1 = *(const ushort8*)(Bp + 8);
    __syncthreads();
    *(ushort8*)&As[sr][sc] = av0;
    *(ushort8*)&As[sr][sc + 8] = av1;
    *(ushort8*)&Bs[sr][sc] = bv0;
    *(ushort8*)&Bs[sr][sc + 8] = bv1;
    __syncthreads();
#pragma unroll
    for (int kh = 0; kh < 2; ++kh) {
      bf16x8 a0 = *(const bf16x8*)(a_rd + kh * 32);
      bf16x8 a1 = *(const bf16x8*)(a_rd + 16 * 72 + kh * 32);
      bf16x8 b0 = *(const bf16x8*)(b_rd + kh * 32);
      bf16x8 b1 = *(const bf16x8*)(b_rd + 16 * 72 + kh * 32);
      acc[0][0] = __builtin_amdgcn_mfma_f32_16x16x32_bf16(a0, b0, acc[0][0], 0, 0, 0);
      acc[0][1] = __builtin_amdgcn_mfma_f32_16x16x32_bf16(a0, b1, acc[0][1], 0, 0, 0);
      acc[1][0] = __builtin_amdgcn_mfma_f32_16x16x32_bf16(a1, b0, acc[1][0], 0, 0, 0);
      acc[1][1] = __builtin_amdgcn_mfma_f32_16x16x32_bf16(a1, b1, acc[1][1], 0, 0, 0);
    }
  }
}

#define EPILOG_VARS                                                   \
  const int lane = threadIdx.x & 63;                                  \
  const int wy = (threadIdx.x >> 7) & 1, wx = (threadIdx.x >> 6) & 1; \
  const int lm = lane & 15, lq = lane >> 4;

// ---------------------------------------------------------------------------
// prep: z=0..5 weight transpose+convert; z=6 x/symbols fp32->bf16
// ---------------------------------------------------------------------------
__global__ __launch_bounds__(256) void prep_kernel(
    const float* __restrict__ x, const float* __restrict__ sym,
    const float* __restrict__ wq, const float* __restrict__ wk,
    const float* __restrict__ wqr, const float* __restrict__ wkr,
    const float* __restrict__ wv, const float* __restrict__ wo,
    ushort* __restrict__ xb, ushort* __restrict__ symb,
    ushort* __restrict__ wqT, ushort* __restrict__ wkT, ushort* __restrict__ wqrT,
    ushort* __restrict__ wkrT, ushort* __restrict__ wvT, ushort* __restrict__ woT) {
  if (blockIdx.z == 6) {
    int b = blockIdx.y * 32 + blockIdx.x;
    if (b >= 512) return;
    int idx = b * 256 + threadIdx.x;
    int i4 = idx << 2;
    float4 v = *(const float4*)(x + i4);
    uint2 o;
    o.x = (unsigned)f2bf(v.x) | ((unsigned)f2bf(v.y) << 16);
    o.y = (unsigned)f2bf(v.z) | ((unsigned)f2bf(v.w) << 16);
    *(uint2*)(xb + i4) = o;
    float4 w = *(const float4*)(sym + i4);
    o.x = (unsigned)f2bf(w.x) | ((unsigned)f2bf(w.y) << 16);
    o.y = (unsigned)f2bf(w.z) | ((unsigned)f2bf(w.w) << 16);
    *(uint2*)(symb + i4) = o;
    return;
  }
  __shared__ ushort t[32][33];
  const float* in;
  ushort* out;
  int N;
  switch (blockIdx.z) {
    case 0: in = wq;  out = wqT;  N = 1024; break;
    case 1: in = wk;  out = wkT;  N = 256;  break;
    case 2: in = wqr; out = wqrT; N = 1024; break;
    case 3: in = wkr; out = wkrT; N = 1024; break;
    case 4: in = wv;  out = wvT;  N = 256;  break;
    default: in = wo; out = woT;  N = 1024; break;
  }
  int n0 = blockIdx.x << 5;
  if (n0 >= N) return;
  int k0 = blockIdx.y << 5;
  int tx = threadIdx.x & 31, ty = threadIdx.x >> 5;
#pragma unroll
  for (int rr = 0; rr < 32; rr += 8)
    t[ty + rr][tx] = f2bf(in[(size_t)(k0 + ty + rr) * N + n0 + tx]);
  __syncthreads();
#pragma unroll
  for (int rr = 0; rr < 32; rr += 8)
    out[(size_t)(n0 + ty + rr) * 1024 + k0 + tx] = t[tx][ty + rr];
}

// ---------------------------------------------------------------------------
// proj: z = {q(+rope), k(+rope), qr, kr, sv(->svT)}
// ---------------------------------------------------------------------------
__global__ __launch_bounds__(256) void proj_mfma(
    const ushort* __restrict__ xb, const ushort* __restrict__ symb,
    const ushort* __restrict__ wqT, const ushort* __restrict__ wkT,
    const ushort* __restrict__ wqrT, const ushort* __restrict__ wkrT,
    const ushort* __restrict__ wvT,
    ushort* __restrict__ qb, ushort* __restrict__ kb, ushort* __restrict__ qrb,
    ushort* __restrict__ krb, ushort* __restrict__ svT,
    const float* __restrict__ fcos, const float* __restrict__ fsin) {
  const int z = blockIdx.z;
  const ushort* A = xb;
  const ushort* Bt;
  ushort* C;
  int N;
  switch (z) {
    case 0: Bt = wqT;  C = qb;  N = 1024; break;
    case 1: Bt = wkT;  C = kb;  N = 256;  break;
    case 2: Bt = wqrT; C = qrb; N = 1024; break;
    case 3: Bt = wkrT; C = krb; N = 1024; break;
    default: A = symb; Bt = wvT; C = svT; N = 256; break;
  }
  const int bn = blockIdx.x << 6;
  if (bn >= N) return;
  const int bm = blockIdx.y << 6;
  floatx4 acc[2][2] = {};
  mfma_body<false>(A + (size_t)bm * 1024, 1024, Bt + (size_t)bn * 1024, 1024, 1024, acc);
  EPILOG_VARS
  if (z <= 1) {
    // fused RoPE: lanes lm, lm^1 hold the (even,odd) pair of d
#pragma unroll
    for (int sy = 0; sy < 2; ++sy)
#pragma unroll
      for (int sx = 0; sx < 2; ++sx)
#pragma unroll
        for (int e = 0; e < 4; ++e) {
          int row = bm + 32 * wy + 16 * sy + 4 * lq + e;
          int col = bn + 32 * wx + 16 * sx + lm;
          float v = acc[sy][sx][e];
          float pv = __shfl_xor(v, 1);
          int d = col & 63, p = d >> 1;
          float c = fcos[(row << 5) + p], s = fsin[(row << 5) + p];
          float o = (d & 1) ? fmaf(pv, s, v * c) : fmaf(v, c, -pv * s);
          C[(size_t)row * N + col] = f2bf(o);
        }
  } else if (z == 4) {
    // write sv transposed: svT[d][j]
#pragma unroll
    for (int sy = 0; sy < 2; ++sy)
#pragma unroll
      for (int sx = 0; sx < 2; ++sx)
#pragma unroll
        for (int e = 0; e < 4; ++e) {
          int row = bm + 32 * wy + 16 * sy + 4 * lq + e;
          int col = bn + 32 * wx + 16 * sx + lm;
          svT[(size_t)col * 512 + row] = f2bf(acc[sy][sx][e]);
        }
  } else {
#pragma unroll
    for (int sy = 0; sy < 2; ++sy)
#pragma unroll
      for (int sx = 0; sx < 2; ++sx)
#pragma unroll
        for (int e = 0; e < 4; ++e) {
          int row = bm + 32 * wy + 16 * sy + 4 * lq + e;
          int col = bn + 32 * wx + 16 * sx + lm;
          C[(size_t)row * N + col] = f2bf(acc[sy][sx][e]);
        }
  }
}

// ---------------------------------------------------------------------------
// relations: block = 32x32 (i,j) x all 16 r. Wave computes r-quads so each
// lane stores rel[i][j][r..r+3] as one float4 -> every 64B line written by
// one wave (full L2 write-combining, no cross-XCD line sharing).
// ---------------------------------------------------------------------------
__global__ __launch_bounds__(256) void relations_mfma(const ushort* __restrict__ qrb,
                                                      const ushort* __restrict__ krb,
                                                      float* __restrict__ rel) {
  const int bi0 = blockIdx.y << 5, bj0 = blockIdx.x << 5;
  const int tid = threadIdx.x, wave = tid >> 6, lane = tid & 63;
  const int lm = lane & 15, lq = lane >> 4;
  const int ib = bi0 + ((wave >> 1) << 4), jb = bj0 + ((wave & 1) << 4);
  const ushort* qrow = qrb + (size_t)(ib + lm) * 1024 + lq * 8;
  const ushort* krow = krb + (size_t)(jb + lm) * 1024 + lq * 8;
#pragma unroll
  for (int rq = 0; rq < 4; ++rq) {
    floatx4 acc[4];
#pragma unroll
    for (int rr = 0; rr < 4; ++rr) {
      int roff = ((rq << 2) + rr) << 6;
      bf16x8 a0 = *(const bf16x8*)(qrow + roff);
      bf16x8 a1 = *(const bf16x8*)(qrow + roff + 32);
      bf16x8 b0 = *(const bf16x8*)(krow + roff);
      bf16x8 b1 = *(const bf16x8*)(krow + roff + 32);
      floatx4 t = {0.f, 0.f, 0.f, 0.f};
      t = __builtin_amdgcn_mfma_f32_16x16x32_bf16(a0, b0, t, 0, 0, 0);
      t = __builtin_amdgcn_mfma_f32_16x16x32_bf16(a1, b1, t, 0, 0, 0);
      acc[rr] = t;
    }
#pragma unroll
    for (int e = 0; e < 4; ++e) {
      int i = ib + 4 * lq + e, j = jb + lm;
      float4 v = make_float4(acc[0][e] * REL_SCALE, acc[1][e] * REL_SCALE,
                             acc[2][e] * REL_SCALE, acc[3][e] * REL_SCALE);
      *(float4*)(rel + ((size_t)i * 512 + j) * 16 + (rq << 2)) = v;
    }
  }
}

// ---------------------------------------------------------------------------
// flash: scores + softmax + attn write + attended_symbols, per (h, 16 i-rows).
// ---------------------------------------------------------------------------
__global__ __launch_bounds__(256) void flash_kernel(const ushort* __restrict__ qb,
                                                    const ushort* __restrict__ kb,
                                                    const ushort* __restrict__ svT,
                                                    float* __restrict__ attn,
                                                    float* __restrict__ asym) {
  __shared__ float S[16][516];   // scaled scores
  __shared__ ushort P[16][520];  // normalized probs, bf16
  const int h = blockIdx.y, i0 = blockIdx.x << 4, kv = h >> 2;
  const int tid = threadIdx.x, wave = tid >> 6, lane = tid & 63;
  const int lm = lane & 15, lq = lane >> 4;
  const int ntiles = blockIdx.x + 1;  // j-tiles of 16 needed (causal)
  // A-frags: q rows i0..i0+15, K=64 (loaded once, straight from global)
  const ushort* qrow = qb + (size_t)(i0 + lm) * 1024 + (h << 6) + lq * 8;
  bf16x8 a0 = *(const bf16x8*)(qrow);
  bf16x8 a1 = *(const bf16x8*)(qrow + 32);
  for (int jt = wave; jt < ntiles; jt += 4) {
    int jb = jt << 4;
    const ushort* krow = kb + (size_t)(jb + lm) * 256 + (kv << 6) + lq * 8;
    bf16x8 b0 = *(const bf16x8*)(krow);
    bf16x8 b1 = *(const bf16x8*)(krow + 32);
    floatx4 acc = {0.f, 0.f, 0.f, 0.f};
    acc = __builtin_amdgcn_mfma_f32_16x16x32_bf16(a0, b0, acc, 0, 0, 0);
    acc = __builtin_amdgcn_mfma_f32_16x16x32_bf16(a1, b1, acc, 0, 0, 0);
#pragma unroll
    for (int e = 0; e < 4; ++e) S[4 * lq + e][jb + lm] = acc[e] * ATTN_SCALE;
  }
  __syncthreads();
  // softmax: 16 threads per row (all within one wave)
  const int row = tid >> 4, t16 = tid & 15;
  const int i = i0 + row;
  const int nj = ntiles << 4;
  float m = -INFINITY;
  for (int s = 0; (s << 6) < nj; ++s) {
    int j4 = (t16 << 2) + (s << 6);
    float4 v = *(const float4*)&S[row][j4];
    if (j4 + 0 <= i) m = fmaxf(m, v.x);
    if (j4 + 1 <= i) m = fmaxf(m, v.y);
    if (j4 + 2 <= i) m = fmaxf(m, v.z);
    if (j4 + 3 <= i) m = fmaxf(m, v.w);
  }
#pragma unroll
  for (int o = 8; o; o >>= 1) m = fmaxf(m, __shfl_xor(m, o, 16));
  float sum = 0.f;
  for (int s = 0; (s << 6) < nj; ++s) {
    int j4 = (t16 << 2) + (s << 6);
    float4 v = *(const float4*)&S[row][j4];
    if (j4 + 0 <= i) sum += __expf(v.x - m);
    if (j4 + 1 <= i) sum += __expf(v.y - m);
    if (j4 + 2 <= i) sum += __expf(v.z - m);
    if (j4 + 3 <= i) sum += __expf(v.w - m);
  }
#pragma unroll
  for (int o = 8; o; o >>= 1) sum += __shfl_xor(sum, o, 16);
  const float inv = 1.f / sum;
  float* arow = attn + (size_t)h * 262144 + (size_t)i * 512;
  for (int s = 0; s < 8; ++s) {
    int j4 = (t16 << 2) + (s << 6);
    float4 o4 = {0.f, 0.f, 0.f, 0.f};
    if (j4 < nj) {
      float4 v = *(const float4*)&S[row][j4];
      o4.x = (j4 + 0 <= i) ? __expf(v.x - m) * inv : 0.f;
      o4.y = (j4 + 1 <= i) ? __expf(v.y - m) * inv : 0.f;
      o4.z = (j4 + 2 <= i) ? __expf(v.z - m) * inv : 0.f;
      o4.w = (j4 + 3 <= i) ? __expf(v.w - m) * inv : 0.f;
    }
    *(float4*)(arow + j4) = o4;  // exact zeros above diagonal
    ushort4v p4;
    p4.x = f2bf(o4.x); p4.y = f2bf(o4.y); p4.z = f2bf(o4.z); p4.w = f2bf(o4.w);
    *(ushort4v*)&P[row][j4] = p4;
  }
  __syncthreads();
  // attended_symbols: asym[16 x 64] = P[16 x nj] @ svT[kv]^T; wave w owns d-range w*16
  const int dbase = wave << 4;
  floatx4 acc2 = {0.f, 0.f, 0.f, 0.f};
  const ushort* svrow = svT + (size_t)((kv << 6) + dbase + lm) * 512;
  const int kmax = (nj + 31) & ~31;  // P is zero-filled to 512, safe
  for (int kt = 0; kt < kmax; kt += 32) {
    bf16x8 pa = *(const bf16x8*)&P[lm][kt + lq * 8];
    bf16x8 pb = *(const bf16x8*)(svrow + kt + lq * 8);
    acc2 = __builtin_amdgcn_mfma_f32_16x16x32_bf16(pa, pb, acc2, 0, 0, 0);
  }
#pragma unroll
  for (int e = 0; e < 4; ++e)
    asym[(size_t)(i0 + 4 * lq + e) * 1024 + (h << 6) + dbase + lm] = acc2[e];
}

// ---------------------------------------------------------------------------
// tker+combine: T[i,h,r] = sum_j attn[h,i,j]*rel[i,j,r]; then
// att[i,h,d] = asym[i,h,d] + sum_r T*wr[r,h*64+d].
// a_s padded to 132 floats/row: kills the old 16-way bank conflict.
// ---------------------------------------------------------------------------
__global__ __launch_bounds__(256) void tker_combine(const float* __restrict__ attn,
                                                    const float* __restrict__ rel,
                                                    const float* __restrict__ asym,
                                                    const float* __restrict__ wr,
                                                    float* __restrict__ att) {
  const int i = blockIdx.x, tid = threadIdx.x;
  __shared__ float a_s[16][132];
  __shared__ float r_s[128][16];
  __shared__ float Ts[16][17];
  const int h = tid >> 4, r = tid & 15;
  float acc = 0.f;
  for (int j0 = 0; j0 <= i; j0 += 128) {
#pragma unroll
    for (int idx = tid; idx < 512; idx += 256) {
      int hh = idx >> 5, j4 = (idx & 31) << 2;
      *(float4*)&a_s[hh][j4] =
          *(const float4*)(attn + (size_t)hh * 262144 + (size_t)i * 512 + j0 + j4);
    }
#pragma unroll
    for (int idx = tid; idx < 512; idx += 256)
      *(float4*)(&r_s[0][0] + (idx << 2)) =
          *(const float4*)(rel + (size_t)i * 8192 + ((size_t)j0 << 4) + (idx << 2));
    __syncthreads();
#pragma unroll 8
    for (int jj = 0; jj < 128; ++jj)  // attn beyond i is exactly 0
      acc = fmaf(a_s[h][jj], r_s[jj][r], acc);
    __syncthreads();
  }
  Ts[h][r] = acc;
  __syncthreads();
  const int hc = tid >> 4, d4 = (tid & 15) << 2;
  float4 o = *(const float4*)(asym + (size_t)i * 1024 + (hc << 6) + d4);
#pragma unroll
  for (int rr = 0; rr < 16; ++rr) {
    float tv = Ts[hc][rr];
    float4 w4 = *(const float4*)(wr + (size_t)rr * 1024 + (hc << 6) + d4);
    o.x = fmaf(tv, w4.x, o.x);
    o.y = fmaf(tv, w4.y, o.y);
    o.z = fmaf(tv, w4.z, o.z);
    o.w = fmaf(tv, w4.w, o.w);
  }
  *(float4*)(att + (size_t)i * 1024 + (hc << 6) + d4) = o;
}

// out = att @ wo (fp32 A converted in staging)
__global__ __launch_bounds__(256) void out_mfma(const float* __restrict__ att,
                                                const ushort* __restrict__ woT,
                                                float* __restrict__ out) {
  const int bn = blockIdx.x << 6, bm = blockIdx.y << 6;
  floatx4 acc[2][2] = {};
  mfma_body<true>(att + (size_t)bm * 1024, 1024, woT + (size_t)bn * 1024, 1024, 1024, acc);
  EPILOG_VARS
#pragma unroll
  for (int sy = 0; sy < 2; ++sy)
#pragma unroll
    for (int sx = 0; sx < 2; ++sx)
#pragma unroll
      for (int e = 0; e < 4; ++e) {
        int row = bm + 32 * wy + 16 * sy + 4 * lq + e;
        int col = bn + 32 * wx + 16 * sx + lm;
        out[(size_t)row * 1024 + col] = acc[sy][sx][e];
      }
}

extern "C" void kernel_launch(void* const* d_in, const int* in_sizes, int n_in,
                              void* d_out, int out_size, void* d_ws, size_t ws_size,
                              hipStream_t stream) {
  const float* x       = (const float*)d_in[0];
  const float* symbols = (const float*)d_in[1];
  const float* fcos    = (const float*)d_in[2];
  const float* fsin    = (const float*)d_in[3];
  const float* wq_attn = (const float*)d_in[4];
  const float* wk_attn = (const float*)d_in[5];
  const float* wq_rel  = (const float*)d_in[6];
  const float* wk_rel  = (const float*)d_in[7];
  const float* wr      = (const float*)d_in[8];
  const float* wv      = (const float*)d_in[9];
  const float* wo      = (const float*)d_in[10];

  float* out  = (float*)d_out;   // 512*1024
  float* attn = out + 524288;    // 16*512*512
  float* rel  = attn + 4194304;  // 512*512*16

  char* wsb = (char*)d_ws;
  const size_t MB = 1 << 20;
  ushort* xb   = (ushort*)(wsb);                        // 1 MB   (dead after proj)
  ushort* symb = (ushort*)(wsb + 1 * MB);               // 1 MB   (dead after proj)
  ushort* wqT  = (ushort*)(wsb + 2 * MB);               // 2 MB   (dead after proj)
  ushort* wkT  = (ushort*)(wsb + 4 * MB);               // 0.5 MB (dead after proj)
  ushort* wqrT = (ushort*)(wsb + 4 * MB + 512 * 1024);  // 2 MB   (dead after proj)
  ushort* wkrT = (ushort*)(wsb + 6 * MB + 512 * 1024);  // 2 MB
  ushort* wvT  = (ushort*)(wsb + 8 * MB + 512 * 1024);  // 0.5 MB
  ushort* woT  = (ushort*)(wsb + 9 * MB);               // 2 MB
  ushort* qb   = (ushort*)(wsb + 11 * MB);              // 1 MB
  ushort* kb   = (ushort*)(wsb + 12 * MB);              // 0.25 MB
  ushort* qrb  = (ushort*)(wsb + 12 * MB + 256 * 1024); // 1 MB
  ushort* krb  = (ushort*)(wsb + 13 * MB + 256 * 1024); // 1 MB
  ushort* svT  = (ushort*)(wsb + 14 * MB + 256 * 1024); // 0.25 MB
  float*  asym = (float*)(wsb + 2 * MB);                // 2 MB, aliases wqT  (written in flash, after proj)
  float*  att  = (float*)(wsb + 4 * MB + 512 * 1024);   // 2 MB, aliases wqrT (written in tker_combine)

  prep_kernel<<<dim3(32, 32, 7), 256, 0, stream>>>(x, symbols, wq_attn, wk_attn,
                                                   wq_rel, wk_rel, wv, wo,
                                                   xb, symb, wqT, wkT, wqrT, wkrT, wvT, woT);
  proj_mfma<<<dim3(16, 8, 5), 256, 0, stream>>>(xb, symb, wqT, wkT, wqrT, wkrT, wvT,
                                                qb, kb, qrb, krb, svT, fcos, fsin);
  relations_mfma<<<dim3(16, 16), 256, 0, stream>>>(qrb, krb, rel);
  flash_kernel<<<dim3(32, 16), 256, 0, stream>>>(qb, kb, svT, attn, asym);
  tker_combine<<<dim3(512), 256, 0, stream>>>(attn, rel, asym, wr, att);
  out_mfma<<<dim3(16, 8), 256, 0, stream>>>(att, woT, out);
}

// Round 4
// 153.781 us; speedup vs baseline: 2.0980x; 1.1009x over previous
//
#include <hip/hip_runtime.h>
#include <math.h>

// B=1, L=512, D=1024, NH=16, NKV=4, NR=16, HD=RD=64
#define ATTN_SCALE 0.125f
#define REL_SCALE 0.125f

using ushort = unsigned short;
using bf16x8 = __attribute__((ext_vector_type(8))) __bf16;
using floatx4 = __attribute__((ext_vector_type(4))) float;
using ushort8 = __attribute__((ext_vector_type(8))) ushort;
using ushort4v = __attribute__((ext_vector_type(4))) ushort;

__device__ __forceinline__ ushort f2bf(float x) {
  unsigned int u = __builtin_bit_cast(unsigned int, x);
  u += 0x7fffu + ((u >> 16) & 1u);  // RNE
  return (ushort)(u >> 16);
}

// ---------------------------------------------------------------------------
// 64x64 MFMA GEMM body (proj): C = A[64][K] * Bt[64][K]^T, all bf16.
// ---------------------------------------------------------------------------
__device__ __forceinline__ void mfma_body(const ushort* __restrict__ A, int lda,
                                          const ushort* __restrict__ Bt, int ldb,
                                          int K, floatx4 (&acc)[2][2]) {
  __shared__ ushort As[64][72];
  __shared__ ushort Bs[64][72];
  const int tid = threadIdx.x;
  const int sr = tid >> 2, sc = (tid & 3) << 4;
  const int lane = tid & 63;
  const int wy = (tid >> 7) & 1, wx = (tid >> 6) & 1;
  const int lm = lane & 15, lq = lane >> 4;
  const ushort* a_rd = &As[32 * wy + lm][lq * 8];
  const ushort* b_rd = &Bs[32 * wx + lm][lq * 8];
  for (int k0 = 0; k0 < K; k0 += 64) {
    const ushort* Ap = A + (size_t)sr * lda + k0 + sc;
    ushort8 av0 = *(const ushort8*)Ap;
    ushort8 av1 = *(const ushort8*)(Ap + 8);
    const ushort* Bp = Bt + (size_t)sr * ldb + k0 + sc;
    ushort8 bv0 = *(const ushort8*)Bp;
    ushort8 bv1 = *(const ushort8*)(Bp + 8);
    __syncthreads();
    *(ushort8*)&As[sr][sc] = av0;
    *(ushort8*)&As[sr][sc + 8] = av1;
    *(ushort8*)&Bs[sr][sc] = bv0;
    *(ushort8*)&Bs[sr][sc + 8] = bv1;
    __syncthreads();
#pragma unroll
    for (int kh = 0; kh < 2; ++kh) {
      bf16x8 a0 = *(const bf16x8*)(a_rd + kh * 32);
      bf16x8 a1 = *(const bf16x8*)(a_rd + 16 * 72 + kh * 32);
      bf16x8 b0 = *(const bf16x8*)(b_rd + kh * 32);
      bf16x8 b1 = *(const bf16x8*)(b_rd + 16 * 72 + kh * 32);
      acc[0][0] = __builtin_amdgcn_mfma_f32_16x16x32_bf16(a0, b0, acc[0][0], 0, 0, 0);
      acc[0][1] = __builtin_amdgcn_mfma_f32_16x16x32_bf16(a0, b1, acc[0][1], 0, 0, 0);
      acc[1][0] = __builtin_amdgcn_mfma_f32_16x16x32_bf16(a1, b0, acc[1][0], 0, 0, 0);
      acc[1][1] = __builtin_amdgcn_mfma_f32_16x16x32_bf16(a1, b1, acc[1][1], 0, 0, 0);
    }
  }
}

#define EPILOG_VARS                                                   \
  const int lane = threadIdx.x & 63;                                  \
  const int wy = (threadIdx.x >> 7) & 1, wx = (threadIdx.x >> 6) & 1; \
  const int lm = lane & 15, lq = lane >> 4;

// ---------------------------------------------------------------------------
// prep: z=0..5 weight transpose+convert; z=6 x/symbols fp32->bf16
// ---------------------------------------------------------------------------
__global__ __launch_bounds__(256) void prep_kernel(
    const float* __restrict__ x, const float* __restrict__ sym,
    const float* __restrict__ wq, const float* __restrict__ wk,
    const float* __restrict__ wqr, const float* __restrict__ wkr,
    const float* __restrict__ wv, const float* __restrict__ wo,
    ushort* __restrict__ xb, ushort* __restrict__ symb,
    ushort* __restrict__ wqT, ushort* __restrict__ wkT, ushort* __restrict__ wqrT,
    ushort* __restrict__ wkrT, ushort* __restrict__ wvT, ushort* __restrict__ woT) {
  if (blockIdx.z == 6) {
    int b = blockIdx.y * 32 + blockIdx.x;
    if (b >= 512) return;
    int idx = b * 256 + threadIdx.x;
    int i4 = idx << 2;
    float4 v = *(const float4*)(x + i4);
    uint2 o;
    o.x = (unsigned)f2bf(v.x) | ((unsigned)f2bf(v.y) << 16);
    o.y = (unsigned)f2bf(v.z) | ((unsigned)f2bf(v.w) << 16);
    *(uint2*)(xb + i4) = o;
    float4 w = *(const float4*)(sym + i4);
    o.x = (unsigned)f2bf(w.x) | ((unsigned)f2bf(w.y) << 16);
    o.y = (unsigned)f2bf(w.z) | ((unsigned)f2bf(w.w) << 16);
    *(uint2*)(symb + i4) = o;
    return;
  }
  __shared__ ushort t[32][33];
  const float* in;
  ushort* out;
  int N;
  switch (blockIdx.z) {
    case 0: in = wq;  out = wqT;  N = 1024; break;
    case 1: in = wk;  out = wkT;  N = 256;  break;
    case 2: in = wqr; out = wqrT; N = 1024; break;
    case 3: in = wkr; out = wkrT; N = 1024; break;
    case 4: in = wv;  out = wvT;  N = 256;  break;
    default: in = wo; out = woT;  N = 1024; break;
  }
  int n0 = blockIdx.x << 5;
  if (n0 >= N) return;
  int k0 = blockIdx.y << 5;
  int tx = threadIdx.x & 31, ty = threadIdx.x >> 5;
#pragma unroll
  for (int rr = 0; rr < 32; rr += 8)
    t[ty + rr][tx] = f2bf(in[(size_t)(k0 + ty + rr) * N + n0 + tx]);
  __syncthreads();
#pragma unroll
  for (int rr = 0; rr < 32; rr += 8)
    out[(size_t)(n0 + ty + rr) * 1024 + k0 + tx] = t[tx][ty + rr];
}

// ---------------------------------------------------------------------------
// proj: z = {q(+rope), k(+rope), qr, kr, sv(->svT)}
// ---------------------------------------------------------------------------
__global__ __launch_bounds__(256) void proj_mfma(
    const ushort* __restrict__ xb, const ushort* __restrict__ symb,
    const ushort* __restrict__ wqT, const ushort* __restrict__ wkT,
    const ushort* __restrict__ wqrT, const ushort* __restrict__ wkrT,
    const ushort* __restrict__ wvT,
    ushort* __restrict__ qb, ushort* __restrict__ kb, ushort* __restrict__ qrb,
    ushort* __restrict__ krb, ushort* __restrict__ svT,
    const float* __restrict__ fcos, const float* __restrict__ fsin) {
  const int z = blockIdx.z;
  const ushort* A = xb;
  const ushort* Bt;
  ushort* C;
  int N;
  switch (z) {
    case 0: Bt = wqT;  C = qb;  N = 1024; break;
    case 1: Bt = wkT;  C = kb;  N = 256;  break;
    case 2: Bt = wqrT; C = qrb; N = 1024; break;
    case 3: Bt = wkrT; C = krb; N = 1024; break;
    default: A = symb; Bt = wvT; C = svT; N = 256; break;
  }
  const int bn = blockIdx.x << 6;
  if (bn >= N) return;
  const int bm = blockIdx.y << 6;
  floatx4 acc[2][2] = {};
  mfma_body(A + (size_t)bm * 1024, 1024, Bt + (size_t)bn * 1024, 1024, 1024, acc);
  EPILOG_VARS
  if (z <= 1) {
    // fused RoPE: lanes lm, lm^1 hold the (even,odd) pair of d
#pragma unroll
    for (int sy = 0; sy < 2; ++sy)
#pragma unroll
      for (int sx = 0; sx < 2; ++sx)
#pragma unroll
        for (int e = 0; e < 4; ++e) {
          int row = bm + 32 * wy + 16 * sy + 4 * lq + e;
          int col = bn + 32 * wx + 16 * sx + lm;
          float v = acc[sy][sx][e];
          float pv = __shfl_xor(v, 1);
          int d = col & 63, p = d >> 1;
          float c = fcos[(row << 5) + p], s = fsin[(row << 5) + p];
          float o = (d & 1) ? fmaf(pv, s, v * c) : fmaf(v, c, -pv * s);
          C[(size_t)row * N + col] = f2bf(o);
        }
  } else if (z == 4) {
    // write sv transposed: svT[d][j]
#pragma unroll
    for (int sy = 0; sy < 2; ++sy)
#pragma unroll
      for (int sx = 0; sx < 2; ++sx)
#pragma unroll
        for (int e = 0; e < 4; ++e) {
          int row = bm + 32 * wy + 16 * sy + 4 * lq + e;
          int col = bn + 32 * wx + 16 * sx + lm;
          svT[(size_t)col * 512 + row] = f2bf(acc[sy][sx][e]);
        }
  } else {
#pragma unroll
    for (int sy = 0; sy < 2; ++sy)
#pragma unroll
      for (int sx = 0; sx < 2; ++sx)
#pragma unroll
        for (int e = 0; e < 4; ++e) {
          int row = bm + 32 * wy + 16 * sy + 4 * lq + e;
          int col = bn + 32 * wx + 16 * sx + lm;
          C[(size_t)row * N + col] = f2bf(acc[sy][sx][e]);
        }
  }
}

// ---------------------------------------------------------------------------
// relflash: bx<512 -> flash (scores+softmax+attn+asym), longest i-tiles first;
//           bx>=512 -> relations (32x32 (i,j) x 16 r, float4 r-stores).
// ---------------------------------------------------------------------------
__global__ __launch_bounds__(256) void relflash_kernel(
    const ushort* __restrict__ qb, const ushort* __restrict__ kb,
    const ushort* __restrict__ svT, const ushort* __restrict__ qrb,
    const ushort* __restrict__ krb, float* __restrict__ attn,
    float* __restrict__ asym, float* __restrict__ rel) {
  __shared__ float S[16][516];
  __shared__ ushort P[16][520];
  const int bx = blockIdx.x;
  const int tid = threadIdx.x, wave = tid >> 6, lane = tid & 63;
  const int lm = lane & 15, lq = lane >> 4;
  if (bx >= 512) {
    // ---- relations ----
    const int b = bx - 512;
    const int bi0 = (b >> 4) << 5, bj0 = (b & 15) << 5;
    const int ib = bi0 + ((wave >> 1) << 4), jb = bj0 + ((wave & 1) << 4);
    const ushort* qrow = qrb + (size_t)(ib + lm) * 1024 + lq * 8;
    const ushort* krow = krb + (size_t)(jb + lm) * 1024 + lq * 8;
#pragma unroll
    for (int rq = 0; rq < 4; ++rq) {
      floatx4 acc[4];
#pragma unroll
      for (int rr = 0; rr < 4; ++rr) {
        int roff = ((rq << 2) + rr) << 6;
        bf16x8 a0 = *(const bf16x8*)(qrow + roff);
        bf16x8 a1 = *(const bf16x8*)(qrow + roff + 32);
        bf16x8 b0 = *(const bf16x8*)(krow + roff);
        bf16x8 b1 = *(const bf16x8*)(krow + roff + 32);
        floatx4 t = {0.f, 0.f, 0.f, 0.f};
        t = __builtin_amdgcn_mfma_f32_16x16x32_bf16(a0, b0, t, 0, 0, 0);
        t = __builtin_amdgcn_mfma_f32_16x16x32_bf16(a1, b1, t, 0, 0, 0);
        acc[rr] = t;
      }
#pragma unroll
      for (int e = 0; e < 4; ++e) {
        int i = ib + 4 * lq + e, j = jb + lm;
        float4 v = make_float4(acc[0][e] * REL_SCALE, acc[1][e] * REL_SCALE,
                               acc[2][e] * REL_SCALE, acc[3][e] * REL_SCALE);
        *(float4*)(rel + ((size_t)i * 512 + j) * 16 + (rq << 2)) = v;
      }
    }
    return;
  }
  // ---- flash ----
  const int h = bx >> 5, it = 31 - (bx & 31);  // longest tiles dispatched first
  const int i0 = it << 4, kv = h >> 2;
  const int ntiles = it + 1;
  const ushort* qrow = qb + (size_t)(i0 + lm) * 1024 + (h << 6) + lq * 8;
  bf16x8 a0 = *(const bf16x8*)(qrow);
  bf16x8 a1 = *(const bf16x8*)(qrow + 32);
  for (int jt = wave; jt < ntiles; jt += 4) {
    int jb = jt << 4;
    const ushort* krow = kb + (size_t)(jb + lm) * 256 + (kv << 6) + lq * 8;
    bf16x8 b0 = *(const bf16x8*)(krow);
    bf16x8 b1 = *(const bf16x8*)(krow + 32);
    floatx4 acc = {0.f, 0.f, 0.f, 0.f};
    acc = __builtin_amdgcn_mfma_f32_16x16x32_bf16(a0, b0, acc, 0, 0, 0);
    acc = __builtin_amdgcn_mfma_f32_16x16x32_bf16(a1, b1, acc, 0, 0, 0);
#pragma unroll
    for (int e = 0; e < 4; ++e) S[4 * lq + e][jb + lm] = acc[e] * ATTN_SCALE;
  }
  __syncthreads();
  const int row = tid >> 4, t16 = tid & 15;
  const int i = i0 + row;
  const int nj = ntiles << 4;
  float m = -INFINITY;
  for (int s = 0; (s << 6) < nj; ++s) {
    int j4 = (t16 << 2) + (s << 6);
    float4 v = *(const float4*)&S[row][j4];
    if (j4 + 0 <= i) m = fmaxf(m, v.x);
    if (j4 + 1 <= i) m = fmaxf(m, v.y);
    if (j4 + 2 <= i) m = fmaxf(m, v.z);
    if (j4 + 3 <= i) m = fmaxf(m, v.w);
  }
#pragma unroll
  for (int o = 8; o; o >>= 1) m = fmaxf(m, __shfl_xor(m, o, 16));
  float sum = 0.f;
  for (int s = 0; (s << 6) < nj; ++s) {
    int j4 = (t16 << 2) + (s << 6);
    float4 v = *(const float4*)&S[row][j4];
    if (j4 + 0 <= i) sum += __expf(v.x - m);
    if (j4 + 1 <= i) sum += __expf(v.y - m);
    if (j4 + 2 <= i) sum += __expf(v.z - m);
    if (j4 + 3 <= i) sum += __expf(v.w - m);
  }
#pragma unroll
  for (int o = 8; o; o >>= 1) sum += __shfl_xor(sum, o, 16);
  const float inv = 1.f / sum;
  float* arow = attn + (size_t)h * 262144 + (size_t)i * 512;
  for (int s = 0; s < 8; ++s) {
    int j4 = (t16 << 2) + (s << 6);
    float4 o4 = {0.f, 0.f, 0.f, 0.f};
    if (j4 < nj) {
      float4 v = *(const float4*)&S[row][j4];
      o4.x = (j4 + 0 <= i) ? __expf(v.x - m) * inv : 0.f;
      o4.y = (j4 + 1 <= i) ? __expf(v.y - m) * inv : 0.f;
      o4.z = (j4 + 2 <= i) ? __expf(v.z - m) * inv : 0.f;
      o4.w = (j4 + 3 <= i) ? __expf(v.w - m) * inv : 0.f;
    }
    *(float4*)(arow + j4) = o4;  // exact zeros above diagonal
    ushort4v p4;
    p4.x = f2bf(o4.x); p4.y = f2bf(o4.y); p4.z = f2bf(o4.z); p4.w = f2bf(o4.w);
    *(ushort4v*)&P[row][j4] = p4;
  }
  __syncthreads();
  // attended_symbols: wave w owns d-range w*16
  const int dbase = wave << 4;
  floatx4 acc2 = {0.f, 0.f, 0.f, 0.f};
  const ushort* svrow = svT + (size_t)((kv << 6) + dbase + lm) * 512;
  const int kmax = (nj + 31) & ~31;  // P zero-filled to 512
  for (int kt = 0; kt < kmax; kt += 32) {
    bf16x8 pa = *(const bf16x8*)&P[lm][kt + lq * 8];
    bf16x8 pb = *(const bf16x8*)(svrow + kt + lq * 8);
    acc2 = __builtin_amdgcn_mfma_f32_16x16x32_bf16(pa, pb, acc2, 0, 0, 0);
  }
#pragma unroll
  for (int e = 0; e < 4; ++e)
    asym[(size_t)(i0 + 4 * lq + e) * 1024 + (h << 6) + dbase + lm] = acc2[e];
}

// ---------------------------------------------------------------------------
// tker+combine: T[i,h,r] = sum_j attn[h,i,j]*rel[i,j,r]; then
// attb[i,h,d] = bf16(asym[i,h,d] + sum_r T*wr[r,h*64+d]).
// rel staged TRANSPOSED (r_s[r][j]) so the hot loop is 2x ds_read_b128/4 FMA.
// ---------------------------------------------------------------------------
__global__ __launch_bounds__(256) void tker_combine(const float* __restrict__ attn,
                                                    const float* __restrict__ rel,
                                                    const float* __restrict__ asym,
                                                    const float* __restrict__ wr,
                                                    ushort* __restrict__ attb) {
  const int i = blockIdx.x, tid = threadIdx.x;
  __shared__ float a_s[16][132];
  __shared__ float r_s[16][132];
  __shared__ float Ts[16][17];
  const int h = tid >> 4, r = tid & 15;
  float acc = 0.f;
  for (int j0 = 0; j0 <= i; j0 += 128) {
#pragma unroll
    for (int idx = tid; idx < 512; idx += 256) {
      int hh = idx >> 5, j4 = (idx & 31) << 2;
      *(float4*)&a_s[hh][j4] =
          *(const float4*)(attn + (size_t)hh * 262144 + (size_t)i * 512 + j0 + j4);
    }
#pragma unroll
    for (int idx = tid; idx < 512; idx += 256) {
      int j = idx >> 2, r4 = (idx & 3) << 2;
      float4 v = *(const float4*)(rel + ((size_t)i * 512 + j0 + j) * 16 + r4);
      r_s[r4 + 0][j] = v.x;
      r_s[r4 + 1][j] = v.y;
      r_s[r4 + 2][j] = v.z;
      r_s[r4 + 3][j] = v.w;
    }
    __syncthreads();
#pragma unroll
    for (int jj = 0; jj < 128; jj += 4) {  // attn beyond i is exactly 0
      float4 a4 = *(const float4*)&a_s[h][jj];
      float4 r4v = *(const float4*)&r_s[r][jj];
      acc = fmaf(a4.x, r4v.x, acc);
      acc = fmaf(a4.y, r4v.y, acc);
      acc = fmaf(a4.z, r4v.z, acc);
      acc = fmaf(a4.w, r4v.w, acc);
    }
    __syncthreads();
  }
  Ts[h][r] = acc;
  __syncthreads();
  const int hc = tid >> 4, d4 = (tid & 15) << 2;
  float4 o = *(const float4*)(asym + (size_t)i * 1024 + (hc << 6) + d4);
#pragma unroll
  for (int rr = 0; rr < 16; ++rr) {
    float tv = Ts[hc][rr];
    float4 w4 = *(const float4*)(wr + (size_t)rr * 1024 + (hc << 6) + d4);
    o.x = fmaf(tv, w4.x, o.x);
    o.y = fmaf(tv, w4.y, o.y);
    o.z = fmaf(tv, w4.z, o.z);
    o.w = fmaf(tv, w4.w, o.w);
  }
  ushort4v ob;
  ob.x = f2bf(o.x); ob.y = f2bf(o.y); ob.z = f2bf(o.z); ob.w = f2bf(o.w);
  *(ushort4v*)(attb + (size_t)i * 1024 + (hc << 6) + d4) = ob;
}

// ---------------------------------------------------------------------------
// out = attb @ wo: 64x32 tiles -> 256 blocks (2x parallelism vs 64x64).
// ---------------------------------------------------------------------------
__global__ __launch_bounds__(256) void out_mfma(const ushort* __restrict__ attb,
                                                const ushort* __restrict__ woT,
                                                float* __restrict__ out) {
  __shared__ ushort As[64][72];
  __shared__ ushort Bs[32][72];
  const int bn = blockIdx.x << 5, bm = blockIdx.y << 6;
  const int tid = threadIdx.x;
  const int sr = tid >> 2, sc = (tid & 3) << 4;  // A stage: 16 elems
  const int br = tid >> 3, bc = (tid & 7) << 3;  // B stage: 8 elems
  const int lane = tid & 63;
  const int wy = (tid >> 7) & 1, wx = (tid >> 6) & 1;
  const int lm = lane & 15, lq = lane >> 4;
  const ushort* a_rd = &As[32 * wy + lm][lq * 8];
  const ushort* b_rd = &Bs[16 * wx + lm][lq * 8];
  floatx4 acc[2] = {};
  for (int k0 = 0; k0 < 1024; k0 += 64) {
    const ushort* Ap = attb + (size_t)(bm + sr) * 1024 + k0 + sc;
    ushort8 av0 = *(const ushort8*)Ap;
    ushort8 av1 = *(const ushort8*)(Ap + 8);
    ushort8 bv = *(const ushort8*)(woT + (size_t)(bn + br) * 1024 + k0 + bc);
    __syncthreads();
    *(ushort8*)&As[sr][sc] = av0;
    *(ushort8*)&As[sr][sc + 8] = av1;
    *(ushort8*)&Bs[br][bc] = bv;
    __syncthreads();
#pragma unroll
    for (int kh = 0; kh < 2; ++kh) {
      bf16x8 a0 = *(const bf16x8*)(a_rd + kh * 32);
      bf16x8 a1 = *(const bf16x8*)(a_rd + 16 * 72 + kh * 32);
      bf16x8 b0 = *(const bf16x8*)(b_rd + kh * 32);
      acc[0] = __builtin_amdgcn_mfma_f32_16x16x32_bf16(a0, b0, acc[0], 0, 0, 0);
      acc[1] = __builtin_amdgcn_mfma_f32_16x16x32_bf16(a1, b0, acc[1], 0, 0, 0);
    }
  }
#pragma unroll
  for (int sy = 0; sy < 2; ++sy)
#pragma unroll
    for (int e = 0; e < 4; ++e) {
      int row = bm + 32 * wy + 16 * sy + 4 * lq + e;
      int col = bn + 16 * wx + lm;
      out[(size_t)row * 1024 + col] = acc[sy][e];
    }
}

extern "C" void kernel_launch(void* const* d_in, const int* in_sizes, int n_in,
                              void* d_out, int out_size, void* d_ws, size_t ws_size,
                              hipStream_t stream) {
  const float* x       = (const float*)d_in[0];
  const float* symbols = (const float*)d_in[1];
  const float* fcos    = (const float*)d_in[2];
  const float* fsin    = (const float*)d_in[3];
  const float* wq_attn = (const float*)d_in[4];
  const float* wk_attn = (const float*)d_in[5];
  const float* wq_rel  = (const float*)d_in[6];
  const float* wk_rel  = (const float*)d_in[7];
  const float* wr      = (const float*)d_in[8];
  const float* wv      = (const float*)d_in[9];
  const float* wo      = (const float*)d_in[10];

  float* out  = (float*)d_out;   // 512*1024
  float* attn = out + 524288;    // 16*512*512
  float* rel  = attn + 4194304;  // 512*512*16

  char* wsb = (char*)d_ws;
  const size_t MB = 1 << 20;
  ushort* xb   = (ushort*)(wsb);                        // 1 MB   (dead after proj)
  ushort* symb = (ushort*)(wsb + 1 * MB);               // 1 MB   (dead after proj)
  ushort* wqT  = (ushort*)(wsb + 2 * MB);               // 2 MB   (dead after proj)
  ushort* wkT  = (ushort*)(wsb + 4 * MB);               // 0.5 MB (dead after proj)
  ushort* wqrT = (ushort*)(wsb + 4 * MB + 512 * 1024);  // 2 MB   (dead after proj)
  ushort* wkrT = (ushort*)(wsb + 6 * MB + 512 * 1024);  // 2 MB
  ushort* wvT  = (ushort*)(wsb + 8 * MB + 512 * 1024);  // 0.5 MB
  ushort* woT  = (ushort*)(wsb + 9 * MB);               // 2 MB
  ushort* qb   = (ushort*)(wsb + 11 * MB);              // 1 MB
  ushort* kb   = (ushort*)(wsb + 12 * MB);              // 0.25 MB
  ushort* qrb  = (ushort*)(wsb + 12 * MB + 256 * 1024); // 1 MB
  ushort* krb  = (ushort*)(wsb + 13 * MB + 256 * 1024); // 1 MB
  ushort* svT  = (ushort*)(wsb + 14 * MB + 256 * 1024); // 0.25 MB
  float*  asym = (float*)(wsb + 2 * MB);                // 2 MB, aliases wqT  (written in relflash)
  ushort* attb = (ushort*)(wsb + 4 * MB + 512 * 1024);  // 1 MB, aliases wqrT (written in tker_combine)

  prep_kernel<<<dim3(32, 32, 7), 256, 0, stream>>>(x, symbols, wq_attn, wk_attn,
                                                   wq_rel, wk_rel, wv, wo,
                                                   xb, symb, wqT, wkT, wqrT, wkrT, wvT, woT);
  proj_mfma<<<dim3(16, 8, 5), 256, 0, stream>>>(xb, symb, wqT, wkT, wqrT, wkrT, wvT,
                                                qb, kb, qrb, krb, svT, fcos, fsin);
  relflash_kernel<<<dim3(768), 256, 0, stream>>>(qb, kb, svT, qrb, krb, attn, asym, rel);
  tker_combine<<<dim3(512), 256, 0, stream>>>(attn, rel, asym, wr, attb);
  out_mfma<<<dim3(32, 8), 256, 0, stream>>>(attb, woT, out);
}